// Round 7
// baseline (264.430 us; speedup 1.0000x reference)
//
#include <hip/hip_runtime.h>
#include <math.h>

#define NBLOCKS 4096
#define BS 256
#define K 8          // float4s per thread; NBLOCKS*BS*K == N/4 == 2^23
#define P2BS 1024    // pass2 block size

typedef float __attribute__((ext_vector_type(4))) vfloat4;
typedef int   __attribute__((ext_vector_type(4))) vint4;

// Partials layout in d_ws (doubles):
// [0*NBLOCKS..) sum_all  [1*NBLOCKS..) sum0  [2*NBLOCKS..) cnt0
// [3*NBLOCKS..) min      [4*NBLOCKS..) max

__global__ __launch_bounds__(BS) void risk_pass1(const float* __restrict__ x,
                                                 const int* __restrict__ y,
                                                 double* __restrict__ ws) {
    const vfloat4* __restrict__ x4 = (const vfloat4*)x;
    const vint4*   __restrict__ y4 = (const vint4*)y;

    // Block-contiguous: block b owns float4 range [b*BS*K, (b+1)*BS*K) (32 KB x + 32 KB y).
    const int base = blockIdx.x * (BS * K) + threadIdx.x;

    float  fs[K], ft[K], fmn[K], fmx[K];
    int    fc[K];

    #pragma unroll
    for (int q = 0; q < K; ++q) {
        // Asymmetric cache policy:
        //   x: non-temporal (HBM stream; no-allocate keeps L3 intact for y)
        //   y: normal load (fully L3-resident after harness restore -> free hits)
        vfloat4 v = __builtin_nontemporal_load(&x4[base + q * BS]);
        vint4   w = y4[base + q * BS];
        fs[q] = (v.x + v.y) + (v.z + v.w);
        float a  = (w.x == 0) ? v.x : 0.0f;
        float b  = (w.y == 0) ? v.y : 0.0f;
        float cc = (w.z == 0) ? v.z : 0.0f;
        float d  = (w.w == 0) ? v.w : 0.0f;
        ft[q] = (a + b) + (cc + d);
        fc[q] = (w.x == 0) + (w.y == 0) + (w.z == 0) + (w.w == 0);
        fmn[q] = fminf(fminf(v.x, v.y), fminf(v.z, v.w));
        fmx[q] = fmaxf(fmaxf(v.x, v.y), fmaxf(v.z, v.w));
    }

    // pairwise combine in fp32, single promotion to f64 per thread per stat
    float s01 = fs[0] + fs[1], s23 = fs[2] + fs[3], s45 = fs[4] + fs[5], s67 = fs[6] + fs[7];
    float t01 = ft[0] + ft[1], t23 = ft[2] + ft[3], t45 = ft[4] + ft[5], t67 = ft[6] + ft[7];
    double sum  = ((double)(s01 + s23)) + ((double)(s45 + s67));
    double sum0 = ((double)(t01 + t23)) + ((double)(t45 + t67));
    int    cnt0 = ((fc[0] + fc[1]) + (fc[2] + fc[3])) + ((fc[4] + fc[5]) + (fc[6] + fc[7]));
    float  mn = fminf(fminf(fminf(fmn[0], fmn[1]), fminf(fmn[2], fmn[3])),
                      fminf(fminf(fmn[4], fmn[5]), fminf(fmn[6], fmn[7])));
    float  mx = fmaxf(fmaxf(fmaxf(fmx[0], fmx[1]), fmaxf(fmx[2], fmx[3])),
                      fmaxf(fmaxf(fmx[4], fmx[5]), fmaxf(fmx[6], fmx[7])));

    // wave (64-lane) reduction
    for (int off = 32; off > 0; off >>= 1) {
        sum  += __shfl_down(sum,  off);
        sum0 += __shfl_down(sum0, off);
        cnt0 += __shfl_down(cnt0, off);
        mn = fminf(mn, __shfl_down(mn, off));
        mx = fmaxf(mx, __shfl_down(mx, off));
    }

    __shared__ double s_sum[BS / 64], s_sum0[BS / 64];
    __shared__ int    s_cnt[BS / 64];
    __shared__ float  s_mn[BS / 64], s_mx[BS / 64];

    int lane = threadIdx.x & 63;
    int wave = threadIdx.x >> 6;
    if (lane == 0) {
        s_sum[wave] = sum; s_sum0[wave] = sum0; s_cnt[wave] = cnt0;
        s_mn[wave] = mn; s_mx[wave] = mx;
    }
    __syncthreads();

    if (threadIdx.x == 0) {
        double bsum = s_sum[0], bsum0 = s_sum0[0];
        int bcnt = s_cnt[0];
        float bmn = s_mn[0], bmx = s_mx[0];
        #pragma unroll
        for (int w = 1; w < BS / 64; ++w) {
            bsum += s_sum[w]; bsum0 += s_sum0[w]; bcnt += s_cnt[w];
            bmn = fminf(bmn, s_mn[w]); bmx = fmaxf(bmx, s_mx[w]);
        }
        ws[0 * NBLOCKS + blockIdx.x] = bsum;
        ws[1 * NBLOCKS + blockIdx.x] = bsum0;
        ws[2 * NBLOCKS + blockIdx.x] = (double)bcnt;
        ws[3 * NBLOCKS + blockIdx.x] = (double)bmn;
        ws[4 * NBLOCKS + blockIdx.x] = (double)bmx;
    }
}

__global__ __launch_bounds__(P2BS) void risk_pass2(const double* __restrict__ ws,
                                                   float* __restrict__ out,
                                                   long long n_total) {
    double sum = 0.0, sum0 = 0.0, cnt0 = 0.0;
    double mn =  INFINITY;
    double mx = -INFINITY;

    for (int i = threadIdx.x; i < NBLOCKS; i += P2BS) {
        sum  += ws[0 * NBLOCKS + i];
        sum0 += ws[1 * NBLOCKS + i];
        cnt0 += ws[2 * NBLOCKS + i];
        mn = fmin(mn, ws[3 * NBLOCKS + i]);
        mx = fmax(mx, ws[4 * NBLOCKS + i]);
    }

    for (int off = 32; off > 0; off >>= 1) {
        sum  += __shfl_down(sum,  off);
        sum0 += __shfl_down(sum0, off);
        cnt0 += __shfl_down(cnt0, off);
        mn = fmin(mn, __shfl_down(mn, off));
        mx = fmax(mx, __shfl_down(mx, off));
    }

    __shared__ double s_sum[P2BS / 64], s_sum0[P2BS / 64], s_cnt[P2BS / 64];
    __shared__ double s_mn[P2BS / 64], s_mx[P2BS / 64];
    int lane = threadIdx.x & 63;
    int wave = threadIdx.x >> 6;
    if (lane == 0) {
        s_sum[wave] = sum; s_sum0[wave] = sum0; s_cnt[wave] = cnt0;
        s_mn[wave] = mn; s_mx[wave] = mx;
    }
    __syncthreads();

    if (threadIdx.x == 0) {
        double tsum = s_sum[0], tsum0 = s_sum0[0], tcnt0 = s_cnt[0];
        double tmn = s_mn[0], tmx = s_mx[0];
        #pragma unroll
        for (int w = 1; w < P2BS / 64; ++w) {
            tsum += s_sum[w]; tsum0 += s_sum0[w]; tcnt0 += s_cnt[w];
            tmn = fmin(tmn, s_mn[w]); tmx = fmax(tmx, s_mx[w]);
        }
        double range = tmx - tmn;
        double n1 = (double)n_total - tcnt0;
        double sum1 = tsum - tsum0;
        double m0 = (tsum0 / tcnt0 - tmn) / range;
        double m1 = (sum1  / n1    - tmn) / range;
        double l = fmin(m0, m1) - fmax(m0, m1);  // = -|m0 - m1|
        out[0] = (float)l;
    }
}

extern "C" void kernel_launch(void* const* d_in, const int* in_sizes, int n_in,
                              void* d_out, int out_size, void* d_ws, size_t ws_size,
                              hipStream_t stream) {
    const float* x = (const float*)d_in[0];
    const int*   y = (const int*)d_in[1];
    float* out = (float*)d_out;
    double* ws = (double*)d_ws;
    long long n = (long long)in_sizes[0];  // 33554432 == NBLOCKS*BS*K*4

    risk_pass1<<<NBLOCKS, BS, 0, stream>>>(x, y, ws);
    risk_pass2<<<1, P2BS, 0, stream>>>(ws, out, n);
}

// Round 8
// 252.375 us; speedup vs baseline: 1.0478x; 1.0478x over previous
//
#include <hip/hip_runtime.h>
#include <math.h>

#define NBLOCKS 4096
#define BS 256
#define K 8          // float4s per thread; NBLOCKS*BS*K == N/4 == 2^23
#define P2BS 1024    // pass2 block size

typedef float __attribute__((ext_vector_type(4))) vfloat4;
typedef int   __attribute__((ext_vector_type(4))) vint4;

// Opaque non-temporal 16B loads: issued back-to-back, no compiler-inserted
// waitcnt between them -> 16 loads (16 KB/wave) genuinely in flight.
__device__ __forceinline__ void ld_nt_f4(const vfloat4* p, vfloat4& d) {
    asm volatile("global_load_dwordx4 %0, %1, off nt" : "=v"(d) : "v"(p));
}
__device__ __forceinline__ void ld_nt_i4(const vint4* p, vint4& d) {
    asm volatile("global_load_dwordx4 %0, %1, off nt" : "=v"(d) : "v"(p));
}

// Partials layout in d_ws (doubles):
// [0*NBLOCKS..) sum_all  [1*NBLOCKS..) sum0  [2*NBLOCKS..) cnt0
// [3*NBLOCKS..) min      [4*NBLOCKS..) max

__global__ __launch_bounds__(BS) void risk_pass1(const float* __restrict__ x,
                                                 const int* __restrict__ y,
                                                 double* __restrict__ ws) {
    const vfloat4* __restrict__ x4 = (const vfloat4*)x;
    const vint4*   __restrict__ y4 = (const vint4*)y;

    // Block-contiguous: block b owns float4 range [b*BS*K, (b+1)*BS*K) (32 KB x + 32 KB y).
    const int base = blockIdx.x * (BS * K) + threadIdx.x;

    vfloat4 v0, v1, v2, v3, v4, v5, v6, v7;
    vint4   w0, w1, w2, w3, w4, w5, w6, w7;

    // Batch-issue all 16 loads (fire-and-forget from the scheduler's view).
    ld_nt_f4(&x4[base + 0 * BS], v0);
    ld_nt_f4(&x4[base + 1 * BS], v1);
    ld_nt_f4(&x4[base + 2 * BS], v2);
    ld_nt_f4(&x4[base + 3 * BS], v3);
    ld_nt_f4(&x4[base + 4 * BS], v4);
    ld_nt_f4(&x4[base + 5 * BS], v5);
    ld_nt_f4(&x4[base + 6 * BS], v6);
    ld_nt_f4(&x4[base + 7 * BS], v7);
    ld_nt_i4(&y4[base + 0 * BS], w0);
    ld_nt_i4(&y4[base + 1 * BS], w1);
    ld_nt_i4(&y4[base + 2 * BS], w2);
    ld_nt_i4(&y4[base + 3 * BS], w3);
    ld_nt_i4(&y4[base + 4 * BS], w4);
    ld_nt_i4(&y4[base + 5 * BS], w5);
    ld_nt_i4(&y4[base + 6 * BS], w6);
    ld_nt_i4(&y4[base + 7 * BS], w7);

    // Single drain; "+v" ties force every consumer below to sit after this wait.
    asm volatile("s_waitcnt vmcnt(0)"
                 : "+v"(v0), "+v"(v1), "+v"(v2), "+v"(v3),
                   "+v"(v4), "+v"(v5), "+v"(v6), "+v"(v7),
                   "+v"(w0), "+v"(w1), "+v"(w2), "+v"(w3),
                   "+v"(w4), "+v"(w5), "+v"(w6), "+v"(w7));

    float fs[K], ft[K], fmn[K], fmx[K];
    int   fc[K];
    {
        const vfloat4 vv[K] = {v0, v1, v2, v3, v4, v5, v6, v7};
        const vint4   wwv[K] = {w0, w1, w2, w3, w4, w5, w6, w7};
        #pragma unroll
        for (int q = 0; q < K; ++q) {
            vfloat4 v = vv[q];
            vint4   w = wwv[q];
            fs[q] = (v.x + v.y) + (v.z + v.w);
            float a  = (w.x == 0) ? v.x : 0.0f;
            float b  = (w.y == 0) ? v.y : 0.0f;
            float cc = (w.z == 0) ? v.z : 0.0f;
            float d  = (w.w == 0) ? v.w : 0.0f;
            ft[q] = (a + b) + (cc + d);
            fc[q] = (w.x == 0) + (w.y == 0) + (w.z == 0) + (w.w == 0);
            fmn[q] = fminf(fminf(v.x, v.y), fminf(v.z, v.w));
            fmx[q] = fmaxf(fmaxf(v.x, v.y), fmaxf(v.z, v.w));
        }
    }

    // pairwise combine in fp32, single promotion to f64 per thread per stat
    float s01 = fs[0] + fs[1], s23 = fs[2] + fs[3], s45 = fs[4] + fs[5], s67 = fs[6] + fs[7];
    float t01 = ft[0] + ft[1], t23 = ft[2] + ft[3], t45 = ft[4] + ft[5], t67 = ft[6] + ft[7];
    double sum  = ((double)(s01 + s23)) + ((double)(s45 + s67));
    double sum0 = ((double)(t01 + t23)) + ((double)(t45 + t67));
    int    cnt0 = ((fc[0] + fc[1]) + (fc[2] + fc[3])) + ((fc[4] + fc[5]) + (fc[6] + fc[7]));
    float  mn = fminf(fminf(fminf(fmn[0], fmn[1]), fminf(fmn[2], fmn[3])),
                      fminf(fminf(fmn[4], fmn[5]), fminf(fmn[6], fmn[7])));
    float  mx = fmaxf(fmaxf(fmaxf(fmx[0], fmx[1]), fmaxf(fmx[2], fmx[3])),
                      fmaxf(fmaxf(fmx[4], fmx[5]), fmaxf(fmx[6], fmx[7])));

    // wave (64-lane) reduction
    for (int off = 32; off > 0; off >>= 1) {
        sum  += __shfl_down(sum,  off);
        sum0 += __shfl_down(sum0, off);
        cnt0 += __shfl_down(cnt0, off);
        mn = fminf(mn, __shfl_down(mn, off));
        mx = fmaxf(mx, __shfl_down(mx, off));
    }

    __shared__ double s_sum[BS / 64], s_sum0[BS / 64];
    __shared__ int    s_cnt[BS / 64];
    __shared__ float  s_mn[BS / 64], s_mx[BS / 64];

    int lane = threadIdx.x & 63;
    int wave = threadIdx.x >> 6;
    if (lane == 0) {
        s_sum[wave] = sum; s_sum0[wave] = sum0; s_cnt[wave] = cnt0;
        s_mn[wave] = mn; s_mx[wave] = mx;
    }
    __syncthreads();

    if (threadIdx.x == 0) {
        double bsum = s_sum[0], bsum0 = s_sum0[0];
        int bcnt = s_cnt[0];
        float bmn = s_mn[0], bmx = s_mx[0];
        #pragma unroll
        for (int w = 1; w < BS / 64; ++w) {
            bsum += s_sum[w]; bsum0 += s_sum0[w]; bcnt += s_cnt[w];
            bmn = fminf(bmn, s_mn[w]); bmx = fmaxf(bmx, s_mx[w]);
        }
        ws[0 * NBLOCKS + blockIdx.x] = bsum;
        ws[1 * NBLOCKS + blockIdx.x] = bsum0;
        ws[2 * NBLOCKS + blockIdx.x] = (double)bcnt;
        ws[3 * NBLOCKS + blockIdx.x] = (double)bmn;
        ws[4 * NBLOCKS + blockIdx.x] = (double)bmx;
    }
}

__global__ __launch_bounds__(P2BS) void risk_pass2(const double* __restrict__ ws,
                                                   float* __restrict__ out,
                                                   long long n_total) {
    double sum = 0.0, sum0 = 0.0, cnt0 = 0.0;
    double mn =  INFINITY;
    double mx = -INFINITY;

    for (int i = threadIdx.x; i < NBLOCKS; i += P2BS) {
        sum  += ws[0 * NBLOCKS + i];
        sum0 += ws[1 * NBLOCKS + i];
        cnt0 += ws[2 * NBLOCKS + i];
        mn = fmin(mn, ws[3 * NBLOCKS + i]);
        mx = fmax(mx, ws[4 * NBLOCKS + i]);
    }

    for (int off = 32; off > 0; off >>= 1) {
        sum  += __shfl_down(sum,  off);
        sum0 += __shfl_down(sum0, off);
        cnt0 += __shfl_down(cnt0, off);
        mn = fmin(mn, __shfl_down(mn, off));
        mx = fmax(mx, __shfl_down(mx, off));
    }

    __shared__ double s_sum[P2BS / 64], s_sum0[P2BS / 64], s_cnt[P2BS / 64];
    __shared__ double s_mn[P2BS / 64], s_mx[P2BS / 64];
    int lane = threadIdx.x & 63;
    int wave = threadIdx.x >> 6;
    if (lane == 0) {
        s_sum[wave] = sum; s_sum0[wave] = sum0; s_cnt[wave] = cnt0;
        s_mn[wave] = mn; s_mx[wave] = mx;
    }
    __syncthreads();

    if (threadIdx.x == 0) {
        double tsum = s_sum[0], tsum0 = s_sum0[0], tcnt0 = s_cnt[0];
        double tmn = s_mn[0], tmx = s_mx[0];
        #pragma unroll
        for (int w = 1; w < P2BS / 64; ++w) {
            tsum += s_sum[w]; tsum0 += s_sum0[w]; tcnt0 += s_cnt[w];
            tmn = fmin(tmn, s_mn[w]); tmx = fmax(tmx, s_mx[w]);
        }
        double range = tmx - tmn;
        double n1 = (double)n_total - tcnt0;
        double sum1 = tsum - tsum0;
        double m0 = (tsum0 / tcnt0 - tmn) / range;
        double m1 = (sum1  / n1    - tmn) / range;
        double l = fmin(m0, m1) - fmax(m0, m1);  // = -|m0 - m1|
        out[0] = (float)l;
    }
}

extern "C" void kernel_launch(void* const* d_in, const int* in_sizes, int n_in,
                              void* d_out, int out_size, void* d_ws, size_t ws_size,
                              hipStream_t stream) {
    const float* x = (const float*)d_in[0];
    const int*   y = (const int*)d_in[1];
    float* out = (float*)d_out;
    double* ws = (double*)d_ws;
    long long n = (long long)in_sizes[0];  // 33554432 == NBLOCKS*BS*K*4

    risk_pass1<<<NBLOCKS, BS, 0, stream>>>(x, y, ws);
    risk_pass2<<<1, P2BS, 0, stream>>>(ws, out, n);
}